// Round 7
// baseline (1932.802 us; speedup 1.0000x reference)
//
#include <hip/hip_runtime.h>
#include <hip/hip_bf16.h>

#define Bb 512
#define Tt 128
#define Nn 256
#define Mm 128

typedef __bf16 bf16_t;
typedef __bf16 bf16x8 __attribute__((ext_vector_type(8)));
typedef float f32x4 __attribute__((ext_vector_type(4)));
typedef unsigned u32x4 __attribute__((ext_vector_type(4)));

__device__ __forceinline__ float bflo(unsigned u) { return __uint_as_float(u << 16); }
__device__ __forceinline__ float bfhi(unsigned u) { return __uint_as_float(u & 0xffff0000u); }

__device__ __forceinline__ float fast_sigmoid(float x) {
  return __builtin_amdgcn_rcpf(1.f + __expf(-x));
}
__device__ __forceinline__ float fast_tanh(float x) {
  float e = __expf(2.f * x);
  return 1.f - 2.f * __builtin_amdgcn_rcpf(e + 1.f);
}

// ---- prep: Whs packed into MFMA B-frag order: [st(8)][kk(8)][lane(64)][8] ----
__global__ void prep_whs(const float* __restrict__ W_e, bf16_t* __restrict__ Whs_pk) {
  int blk = blockIdx.x;            // 0..63 = st*8 + kk
  int st = blk >> 3, kk = blk & 7;
  int lane = threadIdx.x;
  int s = st * 16 + (lane & 15);
  int m0 = kk * 32 + (lane >> 4) * 8;
  bf16_t v[8];
#pragma unroll
  for (int j = 0; j < 8; ++j) v[j] = (bf16_t)W_e[s * 384 + m0 + j];
  *(bf16x8*)(Whs_pk + ((size_t)blk * 64 + lane) * 8) = *(bf16x8*)v;
}

// ---- prep: Wp packed B-frags [gt(32)][kk(12)][lane(64)][8] + permuted bias ----
__global__ void prep_wp(const float* __restrict__ W_ih, const float* __restrict__ W_hh,
                        const float* __restrict__ b_ih, const float* __restrict__ b_hh,
                        bf16_t* __restrict__ Wp_pk, float* __restrict__ bp) {
  int blk = blockIdx.x;            // 0..383 = gt*12 + kk
  int gt = blk / 12, kk = blk % 12;
  int lane = threadIdx.x;
  int r = gt * 16 + (lane & 15);
  int mt = r >> 6, type = (r >> 4) & 3, ml = r & 15;
  int g = type * 128 + mt * 16 + ml;
  int k0 = kk * 32 + (lane >> 4) * 8;
  bf16_t v[8];
#pragma unroll
  for (int j = 0; j < 8; ++j) {
    int k = k0 + j;
    float wv = (k < 256) ? W_ih[g * 256 + k] : W_hh[g * 128 + (k - 256)];
    v[j] = (bf16_t)wv;
  }
  *(bf16x8*)(Wp_pk + ((size_t)blk * 64 + lane) * 8) = *(bf16x8*)v;
  if (kk == 0 && lane < 16) bp[r] = b_ih[g] + b_hh[g];
}

// ---- featproj: F[b][s][n] = bf16( exp( 2 * sum_t X[b][t][n] * W_x[s][t] ) ) ----
__global__ __launch_bounds__(256) void featproj_kernel(
    const float* __restrict__ X, const float* __restrict__ W_e, bf16_t* __restrict__ F) {
  int b  = blockIdx.x >> 2;
  int s0 = (blockIdx.x & 3) << 5;
  int tid = threadIdx.x;
  __shared__ float Xs[32][256];
  float acc[32];
#pragma unroll
  for (int i = 0; i < 32; ++i) acc[i] = 0.f;
  for (int tc = 0; tc < 4; ++tc) {
    __syncthreads();
#pragma unroll
    for (int i = 0; i < 32; ++i)
      Xs[i][tid] = X[((size_t)b * Tt + tc * 32 + i) * Nn + tid];
    __syncthreads();
    for (int tt = 0; tt < 32; ++tt) {
      float xv = Xs[tt][tid];
#pragma unroll
      for (int ss = 0; ss < 32; ++ss)
        acc[ss] = fmaf(W_e[(s0 + ss) * 384 + 256 + tc * 32 + tt], xv, acc[ss]);
    }
  }
#pragma unroll
  for (int ss = 0; ss < 32; ++ss)
    F[((size_t)b * 128 + s0 + ss) * 256 + tid] = (bf16_t)__expf(2.f * acc[ss]);
}

#define BCAST(x) __builtin_bit_cast(bf16x8, x)
#define MFMA16(a, b, c) __builtin_amdgcn_mfma_f32_16x16x32_bf16((a), (b), (c), 0, 0, 0)

// ---- fused recurrence, batch-staggered 4-region pipeline ----
// 256 blocks x 512 threads; weights pinned in (A)GPRs; F resident in LDS.
// Abuf row(b,tau) = b + 2*(tau&1) holds [x~(b,tau) | h(b,tau-1) | c(b,tau-1)].
__global__ __launch_bounds__(512, 2) void fused_kernel(
    const float* __restrict__ X, const bf16_t* __restrict__ F,
    const bf16_t* __restrict__ Whs_pk, const bf16_t* __restrict__ Wp_pk,
    const float* __restrict__ bp, const float* __restrict__ v_e,
    float* __restrict__ out) {
  __shared__ __align__(16) bf16_t Fl[2][128][256];   // 131072 B
  __shared__ __align__(16) bf16_t Abuf[16][520];     // rows 0..3 = parity state rows
  __shared__ float2 avL[2][128];                     // {exp(2a), -2v}
  __shared__ float  Ep[8][256];                      // E partials (alternates b0/b1)

  const int bid = blockIdx.x;
  const int base = 2 * ((bid & 7) * 32 + (bid >> 3));  // XCD-contiguous
  const int tid = threadIdx.x;
  const int w = tid >> 6, lane = tid & 63;
  const int fr = lane & 15, ksel = lane >> 4;

  // ---- pinned weight fragments (anti-remat) ----
  u32x4 wq[48];  // gates: wave w owns g-tiles 4w..4w+3 (wq[j*12+kk])
  u32x4 hq[8];   // Whs:  wave w owns s-tile w
  {
    const u32x4* wp4 = (const u32x4*)Wp_pk;
#pragma unroll
    for (int j = 0; j < 4; ++j)
#pragma unroll
      for (int kk = 0; kk < 12; ++kk)
        wq[j * 12 + kk] = wp4[(size_t)((4 * w + j) * 12 + kk) * 64 + lane];
    const u32x4* wh4 = (const u32x4*)Whs_pk;
#pragma unroll
    for (int kk = 0; kk < 8; ++kk)
      hq[kk] = wh4[(size_t)(w * 8 + kk) * 64 + lane];
#pragma unroll
    for (int i = 0; i < 48; ++i) asm volatile("" : "+v"(wq[i]));
#pragma unroll
    for (int i = 0; i < 8; ++i) asm volatile("" : "+v"(hq[i]));
  }
  float biasr[4];
#pragma unroll
  for (int j = 0; j < 4; ++j) biasr[j] = bp[(4 * w + j) * 16 + fr];
  const float vmr = -2.f * v_e[w * 16 + fr];
  float c0r = 0.f, c1r = 0.f;

  // one-time LDS fill
  {
    const u32x4* src = (const u32x4*)(F + (size_t)base * 32768);
    u32x4* dst = (u32x4*)&Fl[0][0][0];
    for (int i = tid; i < 8192; i += 512) dst[i] = src[i];
    u32x4 z = {0, 0, 0, 0};
    u32x4* ab = (u32x4*)&Abuf[0][0];
    for (int i = tid; i < 1040; i += 512) ab[i] = z;
  }
  if (ksel == 0) avL[0][w * 16 + fr] = make_float2(1.f, vmr);  // a(b0,0)=0
  __syncthreads();

  // h-projection: a(b,tau) from h,c(b,tau-1) in row(b,tau); writes avL[b]
  auto ph1 = [&](int b, int tau) {
    f32x4 pa = {0.f, 0.f, 0.f, 0.f};
#pragma unroll
    for (int kk = 0; kk < 8; ++kk) {
      bf16x8 af = *(const bf16x8*)&Abuf[fr][256 + kk * 32 + ksel * 8];
      pa = MFMA16(af, BCAST(hq[kk]), pa);
    }
    if (ksel == 0) {
      float a = (tau & 1) ? (b ? pa[3] : pa[2]) : (b ? pa[1] : pa[0]);
      avL[b][w * 16 + fr] = make_float2(__expf(2.f * a), vmr);
    }
  };

  // softmax over n (no max pass: |E| <= sum|v| ~ 5) + x_tilde -> row(b,tau)
  auto ph3 = [&](int b, int tau, float4 xp) {
    int n0 = 4 * lane;
    f32x4 E = *(const f32x4*)&Ep[0][n0];
#pragma unroll
    for (int r = 1; r < 8; ++r) E = E + *(const f32x4*)&Ep[r][n0];
    float p0 = __expf(E[0]), p1 = __expf(E[1]), p2 = __expf(E[2]), p3 = __expf(E[3]);
    float tot = (p0 + p1) + (p2 + p3);
#pragma unroll
    for (int off = 32; off; off >>= 1) tot += __shfl_xor(tot, off, 64);
    float ir = __builtin_amdgcn_rcpf(tot);
    bf16_t xb[4];
    xb[0] = (bf16_t)(xp.x * (p0 * ir));
    xb[1] = (bf16_t)(xp.y * (p1 * ir));
    xb[2] = (bf16_t)(xp.z * (p2 * ir));
    xb[3] = (bf16_t)(xp.w * (p3 * ir));
    *(uint2*)&Abuf[b + 2 * (tau & 1)][n0] = *(uint2*)xb;
  };

  // fused region: E-pass for batch ab (VALU) interleaved with gates GEMM +
  // LSTM update for batch gb at step tau (MFMA). do2/do4 gate the halves.
  auto region13 = [&](int ab, int gb, int tau, float& cr, bool do4, bool do2) {
    f32x4 acg0 = {0,0,0,0}, acg1 = {0,0,0,0}, acg2 = {0,0,0,0}, acg3 = {0,0,0,0};
    f32x4 En = {0.f, 0.f, 0.f, 0.f};
    const bf16_t* frow = &Fl[ab][w * 16][0] + 4 * lane;
#pragma unroll
    for (int i = 0; i < 16; ++i) {
      if (do2) {
        float2 avv = avL[ab][w * 16 + i];
        uint2 u = *(const uint2*)(frow + i * 256);
        En[0] = fmaf(avv.y, __builtin_amdgcn_rcpf(fmaf(avv.x, bflo(u.x), 1.f)), En[0]);
        En[1] = fmaf(avv.y, __builtin_amdgcn_rcpf(fmaf(avv.x, bfhi(u.x), 1.f)), En[1]);
        En[2] = fmaf(avv.y, __builtin_amdgcn_rcpf(fmaf(avv.x, bflo(u.y), 1.f)), En[2]);
        En[3] = fmaf(avv.y, __builtin_amdgcn_rcpf(fmaf(avv.x, bfhi(u.y), 1.f)), En[3]);
      }
      if (do4 && i < 12) {
        bf16x8 af = *(const bf16x8*)&Abuf[fr][i * 32 + ksel * 8];
        acg0 = MFMA16(af, BCAST(wq[i]),      acg0);
        acg1 = MFMA16(af, BCAST(wq[12 + i]), acg1);
        acg2 = MFMA16(af, BCAST(wq[24 + i]), acg2);
        acg3 = MFMA16(af, BCAST(wq[36 + i]), acg3);
      }
    }
    if (do2) *(f32x4*)&Ep[w][4 * lane] = En;
    if (do4) {
      int par = tau & 1;
      float g0 = par ? (gb ? acg0[3] : acg0[2]) : (gb ? acg0[1] : acg0[0]);
      float g1 = par ? (gb ? acg1[3] : acg1[2]) : (gb ? acg1[1] : acg1[0]);
      float g2 = par ? (gb ? acg2[3] : acg2[2]) : (gb ? acg2[1] : acg2[0]);
      float g3 = par ? (gb ? acg3[3] : acg3[2]) : (gb ? acg3[1] : acg3[0]);
      float ig = fast_sigmoid(g0 + biasr[0]);
      float fg = fast_sigmoid(g1 + biasr[1]);
      float gg = fast_tanh   (g2 + biasr[2]);
      float og = fast_sigmoid(g3 + biasr[3]);
      float cw = fg * cr + ig * gg;
      float hw = og * fast_tanh(cw);
      cr = cw;
      if (ksel == 0) {
        int m = w * 16 + fr;
        int wr = gb + 2 * ((tau + 1) & 1);
        Abuf[wr][256 + m] = (bf16_t)hw;
        Abuf[wr][384 + m] = (bf16_t)cw;
        out[((size_t)tau * Bb + base + gb) * Mm + m] = hw;
      }
    }
  };

  for (int t = 0; t < Tt; ++t) {
    float4 x0 = make_float4(0.f, 0.f, 0.f, 0.f), x1 = x0;
    if (w == 0) {
      x0 = *(const float4*)(X + ((size_t)(base)     * Tt + t) * Nn + 4 * lane);
      x1 = *(const float4*)(X + ((size_t)(base + 1) * Tt + t) * Nn + 4 * lane);
    }
    // R1: E(b0,t)  ||  gates(b1,t-1)
    region13(0, 1, t - 1, c1r, t > 0, true);
    __syncthreads();
    // R2: h-proj(b1,t)  ||  softmax+x~(b0,t) on wave 0
    ph1(1, t);
    if (w == 0) ph3(0, t, x0);
    __syncthreads();
    // R3: E(b1,t)  ||  gates(b0,t)
    region13(1, 0, t, c0r, true, true);
    __syncthreads();
    // R4: h-proj(b0,t+1)  ||  softmax+x~(b1,t) on wave 0
    ph1(0, t + 1);
    if (w == 0) ph3(1, t, x1);
    __syncthreads();
  }
  // tail: gates(b1, 127)
  region13(0, 1, Tt - 1, c1r, true, false);
}

extern "C" void kernel_launch(void* const* d_in, const int* in_sizes, int n_in,
                              void* d_out, int out_size, void* d_ws, size_t ws_size,
                              hipStream_t stream) {
  const float* X    = (const float*)d_in[0];
  const float* W_e  = (const float*)d_in[1];
  const float* v_e  = (const float*)d_in[2];
  const float* W_ih = (const float*)d_in[3];
  const float* W_hh = (const float*)d_in[4];
  const float* b_ih = (const float*)d_in[5];
  const float* b_hh = (const float*)d_in[6];
  float* out = (float*)d_out;

  char* ws = (char*)d_ws;
  bf16_t* F      = (bf16_t*)ws;                    // 33,554,432
  bf16_t* Whs_pk = (bf16_t*)(ws + 33554432);       // 65,536
  bf16_t* Wp_pk  = (bf16_t*)(ws + 33619968);       // 393,216
  float*  bp     = (float*) (ws + 34013184);       // 2,048

  prep_whs<<<64, 64, 0, stream>>>(W_e, Whs_pk);
  prep_wp<<<384, 64, 0, stream>>>(W_ih, W_hh, b_ih, b_hh, Wp_pk, bp);
  featproj_kernel<<<2048, 256, 0, stream>>>(X, W_e, F);
  fused_kernel<<<256, 512, 0, stream>>>(X, F, Whs_pk, Wp_pk, bp, v_e, out);
}